// Round 1
// 379.422 us; speedup vs baseline: 1.1945x; 1.1945x over previous
//
#include <hip/hip_runtime.h>
#include <hip/hip_bf16.h>

#define N_NODES 100000
#define N_EDGES 1600000
#define DIM_IN  256
#define DIM_H   128

#define NBKT 782          // ceil(N_NODES / 128) buckets of 128 nodes
#define CPAD 16           // ints per padded counter (one cacheline)
#define EPB  8192         // edges per build block
#define NBLK ((N_EDGES + EPB - 1) / EPB)   // 196

typedef __attribute__((ext_vector_type(8))) short short8;
typedef __attribute__((ext_vector_type(4))) float f32x4;

// ------------------------------------------------- edge_index width detect
__global__ __launch_bounds__(1024) void k_detect(const int* __restrict__ e,
                                                 int* __restrict__ flag) {
  __shared__ int s;
  if (threadIdx.x == 0) s = 0;
  __syncthreads();
  atomicOr(&s, e[2 * threadIdx.x + 1]);
  __syncthreads();
  if (threadIdx.x == 0) *flag = (s == 0) ? 1 : 0;
}

__device__ __forceinline__ int get_src(const int* e, int is64, int i) {
  return is64 ? e[2 * i] : e[i];
}
__device__ __forceinline__ int get_dst(const int* e, int is64, int i) {
  return is64 ? e[2 * (N_EDGES + i)] : e[N_EDGES + i];
}

__global__ __launch_bounds__(256) void k_zero(int* __restrict__ p, int n) {
  int i = blockIdx.x * 256 + threadIdx.x;
  if (i < n) p[i] = 0;
}

// ---------------------------------------------------- bucketed CSR build
__global__ __launch_bounds__(1024)
void k_binc(const int* __restrict__ eidx, const int* __restrict__ flag,
            int* __restrict__ bcnt) {
  __shared__ int hist[NBKT];
  const int t = threadIdx.x;
  const int is64 = *flag;
  for (int i = t; i < NBKT; i += 1024) hist[i] = 0;
  __syncthreads();
#pragma unroll
  for (int j = 0; j < EPB / 1024; ++j) {
    int e = blockIdx.x * EPB + j * 1024 + t;
    if (e < N_EDGES) {
      unsigned s = (unsigned)get_src(eidx, is64, e);
      unsigned d = (unsigned)get_dst(eidx, is64, e);
      if (s < N_NODES && d < N_NODES) atomicAdd(&hist[d >> 7], 1);
    }
  }
  __syncthreads();
  for (int i = t; i < NBKT; i += 1024) {
    int h = hist[i];
    if (h) atomicAdd(&bcnt[i * CPAD], h);
  }
}

__global__ __launch_bounds__(1024)
void k_bscan(int* __restrict__ bcnt, int* __restrict__ bbase) {
  __shared__ int sm[1024];
  int t = threadIdx.x;
  int v = (t < NBKT) ? bcnt[t * CPAD] : 0;
  sm[t] = v;
  __syncthreads();
  for (int d = 1; d < 1024; d <<= 1) {
    int u = (t >= d) ? sm[t - d] : 0;
    __syncthreads();
    sm[t] += u;
    __syncthreads();
  }
  if (t < NBKT) {
    int excl = sm[t] - v;
    bbase[t] = excl;
    bcnt[t * CPAD] = excl;
    if (t == NBKT - 1) bbase[NBKT] = sm[t];
  }
}

// record = src | (d&127)<<17   (src < 2^17)
__global__ __launch_bounds__(1024)
void k_bin(const int* __restrict__ eidx, const int* __restrict__ flag,
           int* __restrict__ bcnt, unsigned* __restrict__ ebuf) {
  __shared__ int hist[NBKT];
  __shared__ int cur[NBKT];
  const int t = threadIdx.x;
  const int is64 = *flag;
  for (int i = t; i < NBKT; i += 1024) hist[i] = 0;
  unsigned rec[EPB / 1024];
  int bkt[EPB / 1024];
  __syncthreads();
#pragma unroll
  for (int j = 0; j < EPB / 1024; ++j) {
    int e = blockIdx.x * EPB + j * 1024 + t;
    bkt[j] = -1;
    rec[j] = 0;
    if (e < N_EDGES) {
      unsigned s = (unsigned)get_src(eidx, is64, e);
      unsigned d = (unsigned)get_dst(eidx, is64, e);
      if (s < N_NODES && d < N_NODES) {
        bkt[j] = (int)(d >> 7);
        rec[j] = s | ((d & 127u) << 17);
        atomicAdd(&hist[bkt[j]], 1);
      }
    }
  }
  __syncthreads();
  for (int i = t; i < NBKT; i += 1024) {
    int h = hist[i];
    cur[i] = h ? atomicAdd(&bcnt[i * CPAD], h) : 0;
  }
  __syncthreads();
#pragma unroll
  for (int j = 0; j < EPB / 1024; ++j) {
    if (bkt[j] >= 0) {
      int pos = atomicAdd(&cur[bkt[j]], 1);
      ebuf[pos] = rec[j];
    }
  }
}

__global__ __launch_bounds__(256)
void k_csr(const int* __restrict__ bbase, const unsigned* __restrict__ ebuf,
           int* __restrict__ off, float* __restrict__ dinv,
           int* __restrict__ csr) {
  __shared__ int hist[128];
  __shared__ int scn[128];
  __shared__ int cur[128];
  const int b = blockIdx.x, t = threadIdx.x;
  const int n0 = b << 7;
  const int start = bbase[b], end = bbase[b + 1];
  if (t < 128) hist[t] = 0;
  __syncthreads();
  for (int i = start + t; i < end; i += 256) {
    atomicAdd(&hist[ebuf[i] >> 17], 1);
  }
  __syncthreads();
  if (t < 128) scn[t] = hist[t];
  __syncthreads();
  for (int d = 1; d < 128; d <<= 1) {
    int u = (t < 128 && t >= d) ? scn[t - d] : 0;
    __syncthreads();
    if (t < 128) scn[t] += u;
    __syncthreads();
  }
  if (t < 128) {
    int node = n0 + t;
    if (node < N_NODES) {
      off[node] = start + scn[t];                    // ends
      dinv[node] = rsqrtf(1.0f + (float)hist[t]);
      cur[t] = start + scn[t] - hist[t];             // starts
    }
  }
  __syncthreads();
  for (int i = start + t; i < end; i += 256) {
    unsigned r = ebuf[i];
    int pos = atomicAdd(&cur[r >> 17], 1);
    csr[pos] = (int)(r & 0x1FFFFu);
  }
}

// ---------------------------------------------------------------- bf16 utils
__device__ __forceinline__ ushort f2bf(float f) {
  unsigned u = __float_as_uint(f);
  unsigned r = (u + 0x7fffu + ((u >> 16) & 1u)) >> 16;
  return (ushort)r;
}
__device__ __forceinline__ float bf2f(ushort h) {
  return __uint_as_float(((unsigned)h) << 16);
}
__device__ __forceinline__ float bflo(unsigned u) {
  return __uint_as_float(u << 16);
}
__device__ __forceinline__ float bfhi(unsigned u) {
  return __uint_as_float(u & 0xffff0000u);
}
__device__ __forceinline__ unsigned bfpack(float a, float b) {
  return (unsigned)f2bf(a) | ((unsigned)f2bf(b) << 16);
}

__device__ __forceinline__ void load8(const float* p, float* o) {
  float4 a = reinterpret_cast<const float4*>(p)[0];
  float4 b = reinterpret_cast<const float4*>(p)[1];
  o[0] = a.x; o[1] = a.y; o[2] = a.z; o[3] = a.w;
  o[4] = b.x; o[5] = b.y; o[6] = b.z; o[7] = b.w;
}

// Split weight W[K x 128] into MFMA B-fragment planes (hi, lo).
__global__ __launch_bounds__(256)
void k_bsplit(const float* __restrict__ W, const int CH, ushort* __restrict__ outHi) {
  int idx = blockIdx.x * 256 + threadIdx.x;
  if (idx >= CH * 512) return;
  int n  = idx & 15;
  int qq = (idx >> 4) & 3;
  int nt = (idx >> 6) & 7;
  int c  = idx >> 9;
  int col = nt * 16 + n;
  short8 h8, l8;
#pragma unroll
  for (int j = 0; j < 8; ++j) {
    float v = W[(size_t)(c * 32 + qq * 8 + j) * DIM_H + col];
    ushort hb = f2bf(v);
    ushort lb = f2bf(v - bf2f(hb));
    h8[j] = (short)hb;
    l8[j] = (short)lb;
  }
  ((short8*)outHi)[idx] = h8;
  ((short8*)outHi)[CH * 512 + idx] = l8;
}

// Fused tail weights: Wc = W2 @ Wh  [128 x 2], bc = b2 @ Wh + bh  [2]
__global__ __launch_bounds__(256)
void k_wc(const float* __restrict__ W2, const float* __restrict__ Wh,
          const float* __restrict__ b2, const float* __restrict__ bh,
          float* __restrict__ Wc) {
  const int t = threadIdx.x;
  const int i = t >> 1, j = t & 1;
  float s = 0.f;
#pragma unroll 8
  for (int k = 0; k < DIM_H; ++k) s += W2[(size_t)i * DIM_H + k] * Wh[k * 2 + j];
  Wc[i * 2 + j] = s;
  if (t < 2) {
    float b = 0.f;
    for (int k = 0; k < DIM_H; ++k) b += b2[k] * Wh[k * 2 + t];
    Wc[256 + t] = b + bh[t];
  }
}

// ------------------------------------- MFMA GEMM, fp32 A (split), bf16 out
template <int K>
__global__ __launch_bounds__(256)
void k_gemm_x(const float* __restrict__ A, const ushort* __restrict__ Bfrag,
              const float* __restrict__ bias, ushort* __restrict__ C) {
  constexpr int CH = K / 32;
  __shared__ __align__(16) ushort AhiS[256 * 8];
  __shared__ __align__(16) ushort AloS[256 * 8];
  const int tid = threadIdx.x;
  const int m0 = blockIdx.x * 64;
  const int wave = tid >> 6, lane = tid & 63;
  const int m_l = lane & 15, quad = lane >> 4;
  const int rs = tid >> 2, q = tid & 3;

  f32x4 acc[2][4];
#pragma unroll
  for (int i = 0; i < 2; ++i)
#pragma unroll
    for (int j = 0; j < 4; ++j) acc[i][j] = (f32x4){0.f, 0.f, 0.f, 0.f};

  const short8* Bhi8 = (const short8*)Bfrag;
  const short8* Blo8 = Bhi8 + CH * 512;
  short8* Ah8 = (short8*)AhiS;
  short8* Al8 = (short8*)AloS;

  for (int c = 0; c < CH; ++c) {
    float v[8];
    const int gm = m0 + rs;
    if (gm < N_NODES) {
      load8(&A[(size_t)gm * K + c * 32 + q * 8], v);
    } else {
#pragma unroll
      for (int j = 0; j < 8; ++j) v[j] = 0.f;
    }
    short8 h8, l8;
#pragma unroll
    for (int j = 0; j < 8; ++j) {
      ushort hb = f2bf(v[j]);
      ushort lb = f2bf(v[j] - bf2f(hb));
      h8[j] = (short)hb;
      l8[j] = (short)lb;
    }
    __syncthreads();
    const int ent = (rs >> 4) * 64 + q * 16 + (rs & 15);
    Ah8[ent] = h8;
    Al8[ent] = l8;
    __syncthreads();

    short8 ahi[4], alo[4];
#pragma unroll
    for (int mt = 0; mt < 4; ++mt) {
      ahi[mt] = Ah8[mt * 64 + quad * 16 + m_l];
      alo[mt] = Al8[mt * 64 + quad * 16 + m_l];
    }
#pragma unroll
    for (int ntl = 0; ntl < 2; ++ntl) {
      const int bent = ((c * 8 + wave * 2 + ntl) * 4 + quad) * 16 + m_l;
      short8 bhi = Bhi8[bent];
      short8 blo = Blo8[bent];
#pragma unroll
      for (int mt = 0; mt < 4; ++mt) {
        acc[ntl][mt] = __builtin_amdgcn_mfma_f32_16x16x32_bf16(ahi[mt], bhi, acc[ntl][mt], 0, 0, 0);
        acc[ntl][mt] = __builtin_amdgcn_mfma_f32_16x16x32_bf16(ahi[mt], blo, acc[ntl][mt], 0, 0, 0);
        acc[ntl][mt] = __builtin_amdgcn_mfma_f32_16x16x32_bf16(alo[mt], bhi, acc[ntl][mt], 0, 0, 0);
      }
    }
  }

#pragma unroll
  for (int ntl = 0; ntl < 2; ++ntl) {
    const int colg = (wave * 2 + ntl) * 16 + m_l;
    const float bv = bias[colg];
#pragma unroll
    for (int mt = 0; mt < 4; ++mt) {
#pragma unroll
      for (int r = 0; r < 4; ++r) {
        const int rowg = m0 + mt * 16 + quad * 4 + r;
        if (rowg < N_NODES) {
          float t = fmaxf(acc[ntl][mt][r] + bv, 0.f);  // relu
          C[(size_t)rowg * DIM_H + colg] = f2bf(t);
        }
      }
    }
  }
}

// ------------------------------------- MFMA GEMM, bf16 A, bf16 out, row scale
__global__ __launch_bounds__(256)
void k_gemm_h(const ushort* __restrict__ A, const ushort* __restrict__ Bfrag,
              const float* __restrict__ scale, ushort* __restrict__ C) {
  constexpr int K = DIM_H, CH = K / 32;
  __shared__ __align__(16) ushort AS[256 * 8];
  const int tid = threadIdx.x;
  const int m0 = blockIdx.x * 64;
  const int wave = tid >> 6, lane = tid & 63;
  const int m_l = lane & 15, quad = lane >> 4;
  const int rs = tid >> 2, q = tid & 3;

  f32x4 acc[2][4];
#pragma unroll
  for (int i = 0; i < 2; ++i)
#pragma unroll
    for (int j = 0; j < 4; ++j) acc[i][j] = (f32x4){0.f, 0.f, 0.f, 0.f};

  const short8* Bhi8 = (const short8*)Bfrag;
  const short8* Blo8 = Bhi8 + CH * 512;
  short8* A8 = (short8*)AS;

#pragma unroll
  for (int c = 0; c < CH; ++c) {
    short8 h8 = {0, 0, 0, 0, 0, 0, 0, 0};
    const int gm = m0 + rs;
    if (gm < N_NODES)
      h8 = *reinterpret_cast<const short8*>(&A[(size_t)gm * DIM_H + c * 32 + q * 8]);
    __syncthreads();
    A8[(rs >> 4) * 64 + q * 16 + (rs & 15)] = h8;
    __syncthreads();

    short8 a[4];
#pragma unroll
    for (int mt = 0; mt < 4; ++mt) a[mt] = A8[mt * 64 + quad * 16 + m_l];
#pragma unroll
    for (int ntl = 0; ntl < 2; ++ntl) {
      const int bent = ((c * 8 + wave * 2 + ntl) * 4 + quad) * 16 + m_l;
      short8 bhi = Bhi8[bent];
      short8 blo = Blo8[bent];
#pragma unroll
      for (int mt = 0; mt < 4; ++mt) {
        acc[ntl][mt] = __builtin_amdgcn_mfma_f32_16x16x32_bf16(a[mt], bhi, acc[ntl][mt], 0, 0, 0);
        acc[ntl][mt] = __builtin_amdgcn_mfma_f32_16x16x32_bf16(a[mt], blo, acc[ntl][mt], 0, 0, 0);
      }
    }
  }

#pragma unroll
  for (int ntl = 0; ntl < 2; ++ntl) {
    const int colg = (wave * 2 + ntl) * 16 + m_l;
#pragma unroll
    for (int mt = 0; mt < 4; ++mt) {
#pragma unroll
      for (int r = 0; r < 4; ++r) {
        const int rowg = m0 + mt * 16 + quad * 4 + r;
        if (rowg < N_NODES)
          C[(size_t)rowg * DIM_H + colg] = f2bf(acc[ntl][mt][r] * scale[rowg]);
      }
    }
  }
}

// ------------------------------------------- CSR gather, dual-half ILP,
// fused layer-2+head projection: emits t'[node] = dinv*(h2 @ Wc)  (float2)
// h2 (fp32, in regs) = b1 + dinv[i]*(t[i] + sum t[s]); never materialized.
__global__ __launch_bounds__(256)
void k_aggr_mid(const int* __restrict__ off, const int* __restrict__ csr,
                const ushort* __restrict__ t, const float* __restrict__ dinv,
                const float* __restrict__ bias, const float* __restrict__ Wc,
                float2* __restrict__ tp) {
  int node = blockIdx.x * 4 + (threadIdx.x >> 6);
  if (node >= N_NODES) return;
  const int lane = threadIdx.x & 63;
  const int half = lane >> 5;      // edge-stream parity
  const int col = lane & 31;       // uint2 column (4 bf16)
  const uint2* t2 = (const uint2*)t;
  int start = (node == 0) ? 0 : off[node - 1];
  int end = off[node];
  float a0 = 0.f, a1 = 0.f, a2 = 0.f, a3 = 0.f;
  if (half == 0) {  // self term once
    uint2 u = t2[(size_t)node * 32 + col];
    a0 = bflo(u.x); a1 = bfhi(u.x); a2 = bflo(u.y); a3 = bfhi(u.y);
  }
  int e = start + half;
  for (; e + 6 < end; e += 8) {
    int s0 = csr[e], s1 = csr[e + 2], s2 = csr[e + 4], s3 = csr[e + 6];
    uint2 u0 = t2[(size_t)s0 * 32 + col];
    uint2 u1 = t2[(size_t)s1 * 32 + col];
    uint2 u2 = t2[(size_t)s2 * 32 + col];
    uint2 u3 = t2[(size_t)s3 * 32 + col];
    a0 += (bflo(u0.x) + bflo(u1.x)) + (bflo(u2.x) + bflo(u3.x));
    a1 += (bfhi(u0.x) + bfhi(u1.x)) + (bfhi(u2.x) + bfhi(u3.x));
    a2 += (bflo(u0.y) + bflo(u1.y)) + (bflo(u2.y) + bflo(u3.y));
    a3 += (bfhi(u0.y) + bfhi(u1.y)) + (bfhi(u2.y) + bfhi(u3.y));
  }
  for (; e < end; e += 2) {
    uint2 u = t2[(size_t)csr[e] * 32 + col];
    a0 += bflo(u.x); a1 += bfhi(u.x); a2 += bflo(u.y); a3 += bfhi(u.y);
  }
  // combine the two halves (lanes l and l+32 hold same columns)
  a0 += __shfl_xor(a0, 32);
  a1 += __shfl_xor(a1, 32);
  a2 += __shfl_xor(a2, 32);
  a3 += __shfl_xor(a3, 32);
  // h2 cols 4c..4c+3 in fp32 (no bf16 round) -> dot with Wc[128][2]
  float dn = dinv[node];
  float4 b = ((const float4*)bias)[col];
  float h0 = b.x + dn * a0, h1 = b.y + dn * a1;
  float h2 = b.z + dn * a2, h3 = b.w + dn * a3;
  float4 w0 = ((const float4*)Wc)[2 * col];      // Wc[4c],[4c+1]
  float4 w1 = ((const float4*)Wc)[2 * col + 1];  // Wc[4c+2],[4c+3]
  float s0 = h0 * w0.x + h1 * w0.z + h2 * w1.x + h3 * w1.z;
  float s1 = h0 * w0.y + h1 * w0.w + h2 * w1.y + h3 * w1.w;
#pragma unroll
  for (int o = 16; o > 0; o >>= 1) {  // halves identical; reduce 32 cols
    s0 += __shfl_xor(s0, o);
    s1 += __shfl_xor(s1, o);
  }
  if (lane == 0) tp[node] = make_float2(dn * s0, dn * s1);
}

// ---------------- final gather over 8 B/edge t' (L2-resident, 800 KB table)
// out[d] = bc + dinv[d]*(t'[d] + sum t'[s])
__global__ __launch_bounds__(256)
void k_aggr_out(const int* __restrict__ off, const int* __restrict__ csr,
                const float2* __restrict__ tp, const float* __restrict__ dinv,
                const float* __restrict__ bc, float* __restrict__ out) {
  int node = blockIdx.x * 256 + threadIdx.x;
  if (node >= N_NODES) return;
  int start = (node == 0) ? 0 : off[node - 1];
  int end = off[node];
  float2 self = tp[node];
  float a0 = self.x, a1 = self.y;
  int e = start;
  for (; e + 3 < end; e += 4) {
    int s0 = csr[e], s1 = csr[e + 1], s2 = csr[e + 2], s3 = csr[e + 3];
    float2 v0 = tp[s0];
    float2 v1 = tp[s1];
    float2 v2 = tp[s2];
    float2 v3 = tp[s3];
    a0 += (v0.x + v1.x) + (v2.x + v3.x);
    a1 += (v0.y + v1.y) + (v2.y + v3.y);
  }
  for (; e < end; ++e) {
    float2 v = tp[csr[e]];
    a0 += v.x;
    a1 += v.y;
  }
  float dn = dinv[node];
  reinterpret_cast<float2*>(out)[node] = make_float2(bc[0] + dn * a0, bc[1] + dn * a1);
}

// --------------------------------------------- fp32 fallback (small ws) ----
__global__ __launch_bounds__(256) void k_count(const int* __restrict__ eidx,
                                               const int* __restrict__ flag,
                                               int* __restrict__ off) {
  int e = blockIdx.x * 256 + threadIdx.x;
  int is64 = *flag;
  if (e < N_EDGES) {
    unsigned d = (unsigned)get_dst(eidx, is64, e);
    if (d < N_NODES) atomicAdd(&off[d], 1);
  }
}

__global__ __launch_bounds__(256) void k_dinv_old(const int* __restrict__ off,
                                                  float* __restrict__ dinv) {
  int i = blockIdx.x * 256 + threadIdx.x;
  if (i < N_NODES) dinv[i] = rsqrtf(1.0f + (float)off[i]);
}

template <int K>
__global__ __launch_bounds__(256)
void k_gemm(const float* __restrict__ A, const float* __restrict__ B,
            const float* __restrict__ bias, const float* __restrict__ scale,
            float* __restrict__ C, const int do_relu) {
  __shared__ float As[64][33];
  const int tid = threadIdx.x;
  const int tx = tid & 15;
  const int ty = tid >> 4;
  const int m0 = blockIdx.x * 64;

  float acc[4][8];
#pragma unroll
  for (int i = 0; i < 4; ++i)
#pragma unroll
    for (int j = 0; j < 8; ++j) acc[i][j] = 0.f;

  const int rs = tid >> 2;
  const int ks = (tid & 3) * 8;

  for (int k0 = 0; k0 < K; k0 += 32) {
    float av8[8];
    const int gm = m0 + rs;
    if (gm < N_NODES) {
      load8(&A[(size_t)gm * K + k0 + ks], av8);
    } else {
#pragma unroll
      for (int j = 0; j < 8; ++j) av8[j] = 0.f;
    }
    __syncthreads();
#pragma unroll
    for (int j = 0; j < 8; ++j) As[rs][ks + j] = av8[j];
    __syncthreads();

    const float* Bp = B + (size_t)k0 * DIM_H + tx * 8;
#pragma unroll 4
    for (int k = 0; k < 32; ++k) {
      float bv[8];
      load8(Bp + (size_t)k * DIM_H, bv);
      float av[4];
#pragma unroll
      for (int rr = 0; rr < 4; ++rr) av[rr] = As[ty * 4 + rr][k];
#pragma unroll
      for (int rr = 0; rr < 4; ++rr)
#pragma unroll
        for (int cc = 0; cc < 8; ++cc)
          acc[rr][cc] = fmaf(av[rr], bv[cc], acc[rr][cc]);
    }
  }

  float bs[8];
  if (bias) {
    load8(bias + tx * 8, bs);
  } else {
#pragma unroll
    for (int j = 0; j < 8; ++j) bs[j] = 0.f;
  }
#pragma unroll
  for (int rr = 0; rr < 4; ++rr) {
    const int gm = m0 + ty * 4 + rr;
    if (gm < N_NODES) {
      float sc = scale ? scale[gm] : 1.0f;
      float v[8];
#pragma unroll
      for (int cc = 0; cc < 8; ++cc) {
        float t = acc[rr][cc] + bs[cc];
        if (do_relu) t = fmaxf(t, 0.f);
        v[cc] = t * sc;
      }
      float* Cp = &C[(size_t)gm * DIM_H + tx * 8];
      reinterpret_cast<float4*>(Cp)[0] = make_float4(v[0], v[1], v[2], v[3]);
      reinterpret_cast<float4*>(Cp)[1] = make_float4(v[4], v[5], v[6], v[7]);
    }
  }
}

__global__ __launch_bounds__(256)
void k_aggr_init(const float* __restrict__ t, const float* __restrict__ dinv,
                 const float* __restrict__ bias, float* __restrict__ h) {
  int idx = blockIdx.x * 256 + threadIdx.x;
  if (idx < N_NODES * DIM_H) {
    int i = idx >> 7;
    int c = idx & 127;
    float d = dinv[i];
    h[idx] = bias[c] + t[idx] * d * d;
  }
}

__global__ __launch_bounds__(256)
void k_aggr_edges(const int* __restrict__ eidx, const int* __restrict__ flag,
                  const float* __restrict__ t, const float* __restrict__ dinv,
                  float* __restrict__ h) {
  int e = blockIdx.x * 2 + (threadIdx.x >> 7);
  int c = threadIdx.x & 127;
  int is64 = *flag;
  if (e < N_EDGES) {
    unsigned s = (unsigned)get_src(eidx, is64, e);
    unsigned d = (unsigned)get_dst(eidx, is64, e);
    if (s < N_NODES && d < N_NODES) {
      float nrm = dinv[s] * dinv[d];
      unsafeAtomicAdd(&h[(size_t)d * DIM_H + c], t[(size_t)s * DIM_H + c] * nrm);
    }
  }
}

__global__ __launch_bounds__(256)
void k_head_f32(const float* __restrict__ h, const float* __restrict__ Wh,
                const float* __restrict__ bh, float* __restrict__ out) {
  int node = blockIdx.x * 4 + (threadIdx.x >> 6);
  int lane = threadIdx.x & 63;
  if (node >= N_NODES) return;
  float h0 = h[(size_t)node * DIM_H + lane];
  float h1 = h[(size_t)node * DIM_H + 64 + lane];
  float s0 = h0 * Wh[lane * 2 + 0] + h1 * Wh[(lane + 64) * 2 + 0];
  float s1 = h0 * Wh[lane * 2 + 1] + h1 * Wh[(lane + 64) * 2 + 1];
#pragma unroll
  for (int off = 32; off > 0; off >>= 1) {
    s0 += __shfl_down(s0, off);
    s1 += __shfl_down(s1, off);
  }
  if (lane == 0) {
    reinterpret_cast<float2*>(out)[node] = make_float2(s0 + bh[0], s1 + bh[1]);
  }
}

// ---------------------------------------------------------------- launch
extern "C" void kernel_launch(void* const* d_in, const int* in_sizes, int n_in,
                              void* d_out, int out_size, void* d_ws, size_t ws_size,
                              hipStream_t stream) {
  (void)in_sizes; (void)n_in; (void)out_size;
  const int* eidx = (const int*)d_in[0];
  const float* x  = (const float*)d_in[1];
  const float* Wi = (const float*)d_in[2];
  const float* bi = (const float*)d_in[3];
  const float* W1 = (const float*)d_in[4];
  const float* b1 = (const float*)d_in[5];
  const float* W2 = (const float*)d_in[6];
  const float* b2 = (const float*)d_in[7];
  const float* Wh = (const float*)d_in[8];
  const float* bh = (const float*)d_in[9];
  float* out = (float*)d_out;

  const int gE  = (N_EDGES + 255) / 256;
  const int gM  = (N_NODES + 63) / 64;
  const int gW  = (N_NODES + 3) / 4;

  char* ws = (char*)d_ws;
  int* flag = (int*)ws;
  k_detect<<<1, 1024, 0, stream>>>(eidx, flag);

  const size_t need1 = 65128448;

  if (ws_size >= need1) {
    int*      bcnt  = (int*)(ws + 4096);
    int*      bbase = (int*)(ws + 57344);
    float*    Wc    = (float*)(ws + 61440);    // 128x2 + 2 bias floats
    ushort*   bfWi  = (ushort*)(ws + 65536);
    ushort*   bfW1  = (ushort*)(ws + 196608);
    int*      off   = (int*)(ws + 327680);
    float*    dinv  = (float*)(ws + 728064);
    int*      csr   = (int*)(ws + 1128448);
    unsigned* ebuf  = (unsigned*)(ws + 7528448);
    ushort*   bufA  = (ushort*)(ws + 13928448);
    ushort*   bufB  = (ushort*)(ws + 39528448);
    float2*   tp    = (float2*)(ws + 13928448);  // reuses bufA (h1 dead by then)

    // bucketed CSR build (LDS-aggregated, padded counters)
    k_zero<<<(NBKT * CPAD + 255) / 256, 256, 0, stream>>>(bcnt, NBKT * CPAD);
    k_binc<<<NBLK, 1024, 0, stream>>>(eidx, flag, bcnt);
    k_bscan<<<1, 1024, 0, stream>>>(bcnt, bbase);
    k_bin<<<NBLK, 1024, 0, stream>>>(eidx, flag, bcnt, ebuf);
    k_csr<<<NBKT, 256, 0, stream>>>(bbase, ebuf, off, dinv, csr);

    // weight prep: fragments for Wi, W1; fused tail Wc = W2@Wh, bc = b2@Wh+bh
    k_bsplit<<<16, 256, 0, stream>>>(Wi, 8, bfWi);
    k_bsplit<<<8, 256, 0, stream>>>(W1, 4, bfW1);
    k_wc<<<1, 256, 0, stream>>>(W2, Wh, b2, bh, Wc);

    // h1 = relu(x @ Wi + bi)           [bf16]
    k_gemm_x<DIM_IN><<<gM, 256, 0, stream>>>(x, bfWi, bi, bufA);
    // layer 1: t = (h1 @ W1) * dinv    [bf16]
    k_gemm_h<<<gM, 256, 0, stream>>>(bufA, bfW1, dinv, bufB);
    // layer-1 aggregation + fused (layer2@head) projection -> t' [N x 2 fp32]
    k_aggr_mid<<<gW, 256, 0, stream>>>(off, csr, bufB, dinv, b1, Wc, tp);
    // final 8 B/edge aggregation -> out
    k_aggr_out<<<(N_NODES + 255) / 256, 256, 0, stream>>>(off, csr, tp, dinv,
                                                          Wc + 256, out);
  } else {
    // fallback: fp32 atomic-scatter path (~103 MB)
    const int gN  = (N_NODES + 255) / 256;
    int*   off  = (int*)(ws + 4096);
    float* dinv = (float*)(ws + 404480);
    float* fbA  = (float*)(ws + 804864);
    float* fbB  = (float*)(ws + 804864 + (size_t)N_NODES * DIM_H * 4);
    const int gNH = (N_NODES * DIM_H + 255) / 256;
    const int gE2 = (N_EDGES + 1) / 2;
    k_zero<<<gN, 256, 0, stream>>>(off, N_NODES);
    k_count<<<gE, 256, 0, stream>>>(eidx, flag, off);
    k_dinv_old<<<gN, 256, 0, stream>>>(off, dinv);

    k_gemm<DIM_IN><<<gM, 256, 0, stream>>>(x, Wi, bi, nullptr, fbA, 1);
    k_gemm<DIM_H><<<gM, 256, 0, stream>>>(fbA, W1, nullptr, nullptr, fbB, 0);
    k_aggr_init<<<gNH, 256, 0, stream>>>(fbB, dinv, b1, fbA);
    k_aggr_edges<<<gE2, 256, 0, stream>>>(eidx, flag, fbB, dinv, fbA);
    k_gemm<DIM_H><<<gM, 256, 0, stream>>>(fbA, W2, nullptr, nullptr, fbB, 0);
    k_aggr_init<<<gNH, 256, 0, stream>>>(fbB, dinv, b2, fbA);
    k_aggr_edges<<<gE2, 256, 0, stream>>>(eidx, flag, fbB, dinv, fbA);
    k_head_f32<<<gW, 256, 0, stream>>>(fbA, Wh, bh, out);
  }
}

// Round 2
// 292.045 us; speedup vs baseline: 1.5519x; 1.2992x over previous
//
#include <hip/hip_runtime.h>
#include <hip/hip_bf16.h>

#define N_NODES 100000
#define N_EDGES 1600000
#define DIM_IN  256
#define DIM_H   128

#define NBKT 782          // ceil(N_NODES / 128) buckets of 128 nodes
#define CPAD 16           // ints per padded counter (one cacheline)
#define EPB  8192         // edges per build block
#define NBLK ((N_EDGES + EPB - 1) / EPB)   // 196

typedef __attribute__((ext_vector_type(8))) short short8;
typedef __attribute__((ext_vector_type(4))) float f32x4;

// ------------------------------------------------- edge_index width detect
__global__ __launch_bounds__(1024) void k_detect(const int* __restrict__ e,
                                                 int* __restrict__ flag) {
  __shared__ int s;
  if (threadIdx.x == 0) s = 0;
  __syncthreads();
  atomicOr(&s, e[2 * threadIdx.x + 1]);
  __syncthreads();
  if (threadIdx.x == 0) *flag = (s == 0) ? 1 : 0;
}

__device__ __forceinline__ int get_src(const int* e, int is64, int i) {
  return is64 ? e[2 * i] : e[i];
}
__device__ __forceinline__ int get_dst(const int* e, int is64, int i) {
  return is64 ? e[2 * (N_EDGES + i)] : e[N_EDGES + i];
}

__global__ __launch_bounds__(256) void k_zero(int* __restrict__ p, int n) {
  int i = blockIdx.x * 256 + threadIdx.x;
  if (i < n) p[i] = 0;
}

// ---------------------------------------------------- bucketed CSR build
__global__ __launch_bounds__(1024)
void k_binc(const int* __restrict__ eidx, const int* __restrict__ flag,
            int* __restrict__ bcnt) {
  __shared__ int hist[NBKT];
  const int t = threadIdx.x;
  const int is64 = *flag;
  for (int i = t; i < NBKT; i += 1024) hist[i] = 0;
  __syncthreads();
#pragma unroll
  for (int j = 0; j < EPB / 1024; ++j) {
    int e = blockIdx.x * EPB + j * 1024 + t;
    if (e < N_EDGES) {
      unsigned s = (unsigned)get_src(eidx, is64, e);
      unsigned d = (unsigned)get_dst(eidx, is64, e);
      if (s < N_NODES && d < N_NODES) atomicAdd(&hist[d >> 7], 1);
    }
  }
  __syncthreads();
  for (int i = t; i < NBKT; i += 1024) {
    int h = hist[i];
    if (h) atomicAdd(&bcnt[i * CPAD], h);
  }
}

__global__ __launch_bounds__(1024)
void k_bscan(int* __restrict__ bcnt, int* __restrict__ bbase) {
  __shared__ int sm[1024];
  int t = threadIdx.x;
  int v = (t < NBKT) ? bcnt[t * CPAD] : 0;
  sm[t] = v;
  __syncthreads();
  for (int d = 1; d < 1024; d <<= 1) {
    int u = (t >= d) ? sm[t - d] : 0;
    __syncthreads();
    sm[t] += u;
    __syncthreads();
  }
  if (t < NBKT) {
    int excl = sm[t] - v;
    bbase[t] = excl;
    bcnt[t * CPAD] = excl;
    if (t == NBKT - 1) bbase[NBKT] = sm[t];
  }
}

// record = src | (d&127)<<17   (src < 2^17)
__global__ __launch_bounds__(1024)
void k_bin(const int* __restrict__ eidx, const int* __restrict__ flag,
           int* __restrict__ bcnt, unsigned* __restrict__ ebuf) {
  __shared__ int hist[NBKT];
  __shared__ int cur[NBKT];
  const int t = threadIdx.x;
  const int is64 = *flag;
  for (int i = t; i < NBKT; i += 1024) hist[i] = 0;
  unsigned rec[EPB / 1024];
  int bkt[EPB / 1024];
  __syncthreads();
#pragma unroll
  for (int j = 0; j < EPB / 1024; ++j) {
    int e = blockIdx.x * EPB + j * 1024 + t;
    bkt[j] = -1;
    rec[j] = 0;
    if (e < N_EDGES) {
      unsigned s = (unsigned)get_src(eidx, is64, e);
      unsigned d = (unsigned)get_dst(eidx, is64, e);
      if (s < N_NODES && d < N_NODES) {
        bkt[j] = (int)(d >> 7);
        rec[j] = s | ((d & 127u) << 17);
        atomicAdd(&hist[bkt[j]], 1);
      }
    }
  }
  __syncthreads();
  for (int i = t; i < NBKT; i += 1024) {
    int h = hist[i];
    cur[i] = h ? atomicAdd(&bcnt[i * CPAD], h) : 0;
  }
  __syncthreads();
#pragma unroll
  for (int j = 0; j < EPB / 1024; ++j) {
    if (bkt[j] >= 0) {
      int pos = atomicAdd(&cur[bkt[j]], 1);
      ebuf[pos] = rec[j];
    }
  }
}

__global__ __launch_bounds__(256)
void k_csr(const int* __restrict__ bbase, const unsigned* __restrict__ ebuf,
           int* __restrict__ off, float* __restrict__ dinv,
           int* __restrict__ csr) {
  __shared__ int hist[128];
  __shared__ int scn[128];
  __shared__ int cur[128];
  const int b = blockIdx.x, t = threadIdx.x;
  const int n0 = b << 7;
  const int start = bbase[b], end = bbase[b + 1];
  if (t < 128) hist[t] = 0;
  __syncthreads();
  for (int i = start + t; i < end; i += 256) {
    atomicAdd(&hist[ebuf[i] >> 17], 1);
  }
  __syncthreads();
  if (t < 128) scn[t] = hist[t];
  __syncthreads();
  for (int d = 1; d < 128; d <<= 1) {
    int u = (t < 128 && t >= d) ? scn[t - d] : 0;
    __syncthreads();
    if (t < 128) scn[t] += u;
    __syncthreads();
  }
  if (t < 128) {
    int node = n0 + t;
    if (node < N_NODES) {
      off[node] = start + scn[t];                    // ends
      dinv[node] = rsqrtf(1.0f + (float)hist[t]);
      cur[t] = start + scn[t] - hist[t];             // starts
    }
  }
  __syncthreads();
  for (int i = start + t; i < end; i += 256) {
    unsigned r = ebuf[i];
    int pos = atomicAdd(&cur[r >> 17], 1);
    csr[pos] = (int)(r & 0x1FFFFu);
  }
}

// ---------------------------------------------------------------- bf16 utils
__device__ __forceinline__ ushort f2bf(float f) {
  unsigned u = __float_as_uint(f);
  unsigned r = (u + 0x7fffu + ((u >> 16) & 1u)) >> 16;
  return (ushort)r;
}
__device__ __forceinline__ float bf2f(ushort h) {
  return __uint_as_float(((unsigned)h) << 16);
}

__device__ __forceinline__ void load8(const float* p, float* o) {
  float4 a = reinterpret_cast<const float4*>(p)[0];
  float4 b = reinterpret_cast<const float4*>(p)[1];
  o[0] = a.x; o[1] = a.y; o[2] = a.z; o[3] = a.w;
  o[4] = b.x; o[5] = b.y; o[6] = b.z; o[7] = b.w;
}

// Split weight W[K x 128] into MFMA B-fragment planes (hi, lo).
__global__ __launch_bounds__(256)
void k_bsplit(const float* __restrict__ W, const int CH, ushort* __restrict__ outHi) {
  int idx = blockIdx.x * 256 + threadIdx.x;
  if (idx >= CH * 512) return;
  int n  = idx & 15;
  int qq = (idx >> 4) & 3;
  int nt = (idx >> 6) & 7;
  int c  = idx >> 9;
  int col = nt * 16 + n;
  short8 h8, l8;
#pragma unroll
  for (int j = 0; j < 8; ++j) {
    float v = W[(size_t)(c * 32 + qq * 8 + j) * DIM_H + col];
    ushort hb = f2bf(v);
    ushort lb = f2bf(v - bf2f(hb));
    h8[j] = (short)hb;
    l8[j] = (short)lb;
  }
  ((short8*)outHi)[idx] = h8;
  ((short8*)outHi)[CH * 512 + idx] = l8;
}

// Fully collapsed tail weights:
//   Wcc = W1 @ (W2 @ Wh)  [128 x 2]   (everything after h1 is linear)
//   c1  = b1 @ (W2 @ Wh)  [2]
//   bc  = b2 @ Wh + bh    [2]
// Stored: Wcc[0..255], c1 at [256..257], bc at [258..259]
__global__ __launch_bounds__(256)
void k_wcc(const float* __restrict__ W1, const float* __restrict__ W2,
           const float* __restrict__ Wh, const float* __restrict__ b1,
           const float* __restrict__ b2, const float* __restrict__ bh,
           float* __restrict__ Wcc) {
  __shared__ float Wc2s[DIM_H][2];
  const int t = threadIdx.x;
  const int i = t >> 1, j = t & 1;
  float s = 0.f;
#pragma unroll 4
  for (int m = 0; m < DIM_H; ++m) s += W2[(size_t)i * DIM_H + m] * Wh[m * 2 + j];
  Wc2s[i][j] = s;
  __syncthreads();
  float c = 0.f;
#pragma unroll 4
  for (int k = 0; k < DIM_H; ++k) c += W1[(size_t)i * DIM_H + k] * Wc2s[k][j];
  Wcc[i * 2 + j] = c;
  if (t < 2) {
    float a = 0.f, b = 0.f;
    for (int k = 0; k < DIM_H; ++k) {
      a += b1[k] * Wc2s[k][t];
      b += b2[k] * Wh[k * 2 + t];
    }
    Wcc[256 + t] = a;           // c1
    Wcc[258 + t] = b + bh[t];   // bc
  }
}

// ------------- MFMA GEMM (fp32 A via hi/lo split) + fused z = relu(.)@Wcc
// Emits tbl[row] = (dinv*z0, dinv*z1, dinv, 0); h1 never materialized.
template <int K>
__global__ __launch_bounds__(256)
void k_gemm_xz(const float* __restrict__ A, const ushort* __restrict__ Bfrag,
               const float* __restrict__ bias, const float* __restrict__ Wcc,
               const float* __restrict__ dinv, float4* __restrict__ tbl) {
  constexpr int CH = K / 32;
  __shared__ __align__(16) ushort AhiS[256 * 8];
  __shared__ __align__(16) ushort AloS[256 * 8];
  __shared__ float zred[2][4][4][4][4];  // [j][wave][quad][mt][r]
  const int tid = threadIdx.x;
  const int m0 = blockIdx.x * 64;
  const int wave = tid >> 6, lane = tid & 63;
  const int m_l = lane & 15, quad = lane >> 4;
  const int rs = tid >> 2, q = tid & 3;

  f32x4 acc[2][4];
#pragma unroll
  for (int i = 0; i < 2; ++i)
#pragma unroll
    for (int j = 0; j < 4; ++j) acc[i][j] = (f32x4){0.f, 0.f, 0.f, 0.f};

  const short8* Bhi8 = (const short8*)Bfrag;
  const short8* Blo8 = Bhi8 + CH * 512;
  short8* Ah8 = (short8*)AhiS;
  short8* Al8 = (short8*)AloS;

  for (int c = 0; c < CH; ++c) {
    float v[8];
    const int gm = m0 + rs;
    if (gm < N_NODES) {
      load8(&A[(size_t)gm * K + c * 32 + q * 8], v);
    } else {
#pragma unroll
      for (int j = 0; j < 8; ++j) v[j] = 0.f;
    }
    short8 h8, l8;
#pragma unroll
    for (int j = 0; j < 8; ++j) {
      ushort hb = f2bf(v[j]);
      ushort lb = f2bf(v[j] - bf2f(hb));
      h8[j] = (short)hb;
      l8[j] = (short)lb;
    }
    __syncthreads();
    const int ent = (rs >> 4) * 64 + q * 16 + (rs & 15);
    Ah8[ent] = h8;
    Al8[ent] = l8;
    __syncthreads();

    short8 ahi[4], alo[4];
#pragma unroll
    for (int mt = 0; mt < 4; ++mt) {
      ahi[mt] = Ah8[mt * 64 + quad * 16 + m_l];
      alo[mt] = Al8[mt * 64 + quad * 16 + m_l];
    }
#pragma unroll
    for (int ntl = 0; ntl < 2; ++ntl) {
      const int bent = ((c * 8 + wave * 2 + ntl) * 4 + quad) * 16 + m_l;
      short8 bhi = Bhi8[bent];
      short8 blo = Blo8[bent];
#pragma unroll
      for (int mt = 0; mt < 4; ++mt) {
        acc[ntl][mt] = __builtin_amdgcn_mfma_f32_16x16x32_bf16(ahi[mt], bhi, acc[ntl][mt], 0, 0, 0);
        acc[ntl][mt] = __builtin_amdgcn_mfma_f32_16x16x32_bf16(ahi[mt], blo, acc[ntl][mt], 0, 0, 0);
        acc[ntl][mt] = __builtin_amdgcn_mfma_f32_16x16x32_bf16(alo[mt], bhi, acc[ntl][mt], 0, 0, 0);
      }
    }
  }

  // ---- fused epilogue: p = relu(acc + bias) @ Wcc, reduced over 128 cols
  float p0[4][4], p1[4][4];
#pragma unroll
  for (int mt = 0; mt < 4; ++mt)
#pragma unroll
    for (int r = 0; r < 4; ++r) { p0[mt][r] = 0.f; p1[mt][r] = 0.f; }
#pragma unroll
  for (int ntl = 0; ntl < 2; ++ntl) {
    const int colg = (wave * 2 + ntl) * 16 + m_l;
    const float bv = bias[colg];
    const float w0 = Wcc[colg * 2 + 0];
    const float w1 = Wcc[colg * 2 + 1];
#pragma unroll
    for (int mt = 0; mt < 4; ++mt)
#pragma unroll
      for (int r = 0; r < 4; ++r) {
        float hv = fmaxf(acc[ntl][mt][r] + bv, 0.f);  // relu(h1)
        p0[mt][r] += hv * w0;
        p1[mt][r] += hv * w1;
      }
  }
  // reduce across the 16 m_l lanes within each quad (cols of this wave)
#pragma unroll
  for (int o = 1; o < 16; o <<= 1) {
#pragma unroll
    for (int mt = 0; mt < 4; ++mt)
#pragma unroll
      for (int r = 0; r < 4; ++r) {
        p0[mt][r] += __shfl_xor(p0[mt][r], o);
        p1[mt][r] += __shfl_xor(p1[mt][r], o);
      }
  }
  if (m_l == 0) {
#pragma unroll
    for (int mt = 0; mt < 4; ++mt)
#pragma unroll
      for (int r = 0; r < 4; ++r) {
        zred[0][wave][quad][mt][r] = p0[mt][r];
        zred[1][wave][quad][mt][r] = p1[mt][r];
      }
  }
  __syncthreads();
  if (tid < 64) {
    // rowg = m0 + mt*16 + quad*4 + r  ==  m0 + tid
    const int mt = tid >> 4, qd = (tid >> 2) & 3, r = tid & 3;
    const int rowg = m0 + tid;
    if (rowg < N_NODES) {
      float s0 = zred[0][0][qd][mt][r] + zred[0][1][qd][mt][r] +
                 zred[0][2][qd][mt][r] + zred[0][3][qd][mt][r];
      float s1 = zred[1][0][qd][mt][r] + zred[1][1][qd][mt][r] +
                 zred[1][2][qd][mt][r] + zred[1][3][qd][mt][r];
      float dn = dinv[rowg];
      tbl[rowg] = make_float4(dn * s0, dn * s1, dn, 0.f);
    }
  }
}

// ---------------- pass 1: yt[d] = dinv²·(zs[d] + Σ zs[s]),  g[d] = dinv·(Σ dinv + dinv)
// tbl[s] = (zs0, zs1, dinv[s], 0), 16 B/edge gather on a 1.6 MB (L2-resident) table.
__global__ __launch_bounds__(256)
void k_aggr1(const int* __restrict__ off, const int* __restrict__ csr,
             const float4* __restrict__ tbl, float2* __restrict__ tb2,
             float* __restrict__ g) {
  int node = blockIdx.x * 256 + threadIdx.x;
  if (node >= N_NODES) return;
  int start = (node == 0) ? 0 : off[node - 1];
  int end = off[node];
  float4 self = tbl[node];
  float s0 = self.x, s1 = self.y, sd = self.z;
  int e = start;
  for (; e + 3 < end; e += 4) {
    int i0 = csr[e], i1 = csr[e + 1], i2 = csr[e + 2], i3 = csr[e + 3];
    float4 v0 = tbl[i0];
    float4 v1 = tbl[i1];
    float4 v2 = tbl[i2];
    float4 v3 = tbl[i3];
    s0 += (v0.x + v1.x) + (v2.x + v3.x);
    s1 += (v0.y + v1.y) + (v2.y + v3.y);
    sd += (v0.z + v1.z) + (v2.z + v3.z);
  }
  for (; e < end; ++e) {
    float4 v = tbl[csr[e]];
    s0 += v.x; s1 += v.y; sd += v.z;
  }
  float dn = self.z;
  tb2[node] = make_float2(dn * dn * s0, dn * dn * s1);
  g[node] = dn * sd;
}

// ---------------- pass 2: out[d] = dinv·(yt[d] + Σ yt[s]) + g[d]·c1 + bc
// 8 B/edge gather on an 800 KB table. tail = {c1[0],c1[1],bc[0],bc[1]}.
__global__ __launch_bounds__(256)
void k_aggr2(const int* __restrict__ off, const int* __restrict__ csr,
             const float2* __restrict__ tb2, const float* __restrict__ dinv,
             const float* __restrict__ g, const float* __restrict__ tail,
             float* __restrict__ out) {
  int node = blockIdx.x * 256 + threadIdx.x;
  if (node >= N_NODES) return;
  int start = (node == 0) ? 0 : off[node - 1];
  int end = off[node];
  float2 self = tb2[node];
  float s0 = self.x, s1 = self.y;
  int e = start;
  for (; e + 3 < end; e += 4) {
    int i0 = csr[e], i1 = csr[e + 1], i2 = csr[e + 2], i3 = csr[e + 3];
    float2 v0 = tb2[i0];
    float2 v1 = tb2[i1];
    float2 v2 = tb2[i2];
    float2 v3 = tb2[i3];
    s0 += (v0.x + v1.x) + (v2.x + v3.x);
    s1 += (v0.y + v1.y) + (v2.y + v3.y);
  }
  for (; e < end; ++e) {
    float2 v = tb2[csr[e]];
    s0 += v.x; s1 += v.y;
  }
  float dn = dinv[node], gv = g[node];
  float o0 = dn * s0 + gv * tail[0] + tail[2];
  float o1 = dn * s1 + gv * tail[1] + tail[3];
  reinterpret_cast<float2*>(out)[node] = make_float2(o0, o1);
}

// --------------------------------------------- fp32 fallback (small ws) ----
__global__ __launch_bounds__(256) void k_count(const int* __restrict__ eidx,
                                               const int* __restrict__ flag,
                                               int* __restrict__ off) {
  int e = blockIdx.x * 256 + threadIdx.x;
  int is64 = *flag;
  if (e < N_EDGES) {
    unsigned d = (unsigned)get_dst(eidx, is64, e);
    if (d < N_NODES) atomicAdd(&off[d], 1);
  }
}

__global__ __launch_bounds__(256) void k_dinv_old(const int* __restrict__ off,
                                                  float* __restrict__ dinv) {
  int i = blockIdx.x * 256 + threadIdx.x;
  if (i < N_NODES) dinv[i] = rsqrtf(1.0f + (float)off[i]);
}

template <int K>
__global__ __launch_bounds__(256)
void k_gemm(const float* __restrict__ A, const float* __restrict__ B,
            const float* __restrict__ bias, const float* __restrict__ scale,
            float* __restrict__ C, const int do_relu) {
  __shared__ float As[64][33];
  const int tid = threadIdx.x;
  const int tx = tid & 15;
  const int ty = tid >> 4;
  const int m0 = blockIdx.x * 64;

  float acc[4][8];
#pragma unroll
  for (int i = 0; i < 4; ++i)
#pragma unroll
    for (int j = 0; j < 8; ++j) acc[i][j] = 0.f;

  const int rs = tid >> 2;
  const int ks = (tid & 3) * 8;

  for (int k0 = 0; k0 < K; k0 += 32) {
    float av8[8];
    const int gm = m0 + rs;
    if (gm < N_NODES) {
      load8(&A[(size_t)gm * K + k0 + ks], av8);
    } else {
#pragma unroll
      for (int j = 0; j < 8; ++j) av8[j] = 0.f;
    }
    __syncthreads();
#pragma unroll
    for (int j = 0; j < 8; ++j) As[rs][ks + j] = av8[j];
    __syncthreads();

    const float* Bp = B + (size_t)k0 * DIM_H + tx * 8;
#pragma unroll 4
    for (int k = 0; k < 32; ++k) {
      float bv[8];
      load8(Bp + (size_t)k * DIM_H, bv);
      float av[4];
#pragma unroll
      for (int rr = 0; rr < 4; ++rr) av[rr] = As[ty * 4 + rr][k];
#pragma unroll
      for (int rr = 0; rr < 4; ++rr)
#pragma unroll
        for (int cc = 0; cc < 8; ++cc)
          acc[rr][cc] = fmaf(av[rr], bv[cc], acc[rr][cc]);
    }
  }

  float bs[8];
  if (bias) {
    load8(bias + tx * 8, bs);
  } else {
#pragma unroll
    for (int j = 0; j < 8; ++j) bs[j] = 0.f;
  }
#pragma unroll
  for (int rr = 0; rr < 4; ++rr) {
    const int gm = m0 + ty * 4 + rr;
    if (gm < N_NODES) {
      float sc = scale ? scale[gm] : 1.0f;
      float v[8];
#pragma unroll
      for (int cc = 0; cc < 8; ++cc) {
        float t = acc[rr][cc] + bs[cc];
        if (do_relu) t = fmaxf(t, 0.f);
        v[cc] = t * sc;
      }
      float* Cp = &C[(size_t)gm * DIM_H + tx * 8];
      reinterpret_cast<float4*>(Cp)[0] = make_float4(v[0], v[1], v[2], v[3]);
      reinterpret_cast<float4*>(Cp)[1] = make_float4(v[4], v[5], v[6], v[7]);
    }
  }
}

__global__ __launch_bounds__(256)
void k_aggr_init(const float* __restrict__ t, const float* __restrict__ dinv,
                 const float* __restrict__ bias, float* __restrict__ h) {
  int idx = blockIdx.x * 256 + threadIdx.x;
  if (idx < N_NODES * DIM_H) {
    int i = idx >> 7;
    int c = idx & 127;
    float d = dinv[i];
    h[idx] = bias[c] + t[idx] * d * d;
  }
}

__global__ __launch_bounds__(256)
void k_aggr_edges(const int* __restrict__ eidx, const int* __restrict__ flag,
                  const float* __restrict__ t, const float* __restrict__ dinv,
                  float* __restrict__ h) {
  int e = blockIdx.x * 2 + (threadIdx.x >> 7);
  int c = threadIdx.x & 127;
  int is64 = *flag;
  if (e < N_EDGES) {
    unsigned s = (unsigned)get_src(eidx, is64, e);
    unsigned d = (unsigned)get_dst(eidx, is64, e);
    if (s < N_NODES && d < N_NODES) {
      float nrm = dinv[s] * dinv[d];
      unsafeAtomicAdd(&h[(size_t)d * DIM_H + c], t[(size_t)s * DIM_H + c] * nrm);
    }
  }
}

__global__ __launch_bounds__(256)
void k_head_f32(const float* __restrict__ h, const float* __restrict__ Wh,
                const float* __restrict__ bh, float* __restrict__ out) {
  int node = blockIdx.x * 4 + (threadIdx.x >> 6);
  int lane = threadIdx.x & 63;
  if (node >= N_NODES) return;
  float h0 = h[(size_t)node * DIM_H + lane];
  float h1 = h[(size_t)node * DIM_H + 64 + lane];
  float s0 = h0 * Wh[lane * 2 + 0] + h1 * Wh[(lane + 64) * 2 + 0];
  float s1 = h0 * Wh[lane * 2 + 1] + h1 * Wh[(lane + 64) * 2 + 1];
#pragma unroll
  for (int off = 32; off > 0; off >>= 1) {
    s0 += __shfl_down(s0, off);
    s1 += __shfl_down(s1, off);
  }
  if (lane == 0) {
    reinterpret_cast<float2*>(out)[node] = make_float2(s0 + bh[0], s1 + bh[1]);
  }
}

// ---------------------------------------------------------------- launch
extern "C" void kernel_launch(void* const* d_in, const int* in_sizes, int n_in,
                              void* d_out, int out_size, void* d_ws, size_t ws_size,
                              hipStream_t stream) {
  (void)in_sizes; (void)n_in; (void)out_size;
  const int* eidx = (const int*)d_in[0];
  const float* x  = (const float*)d_in[1];
  const float* Wi = (const float*)d_in[2];
  const float* bi = (const float*)d_in[3];
  const float* W1 = (const float*)d_in[4];
  const float* b1 = (const float*)d_in[5];
  const float* W2 = (const float*)d_in[6];
  const float* b2 = (const float*)d_in[7];
  const float* Wh = (const float*)d_in[8];
  const float* bh = (const float*)d_in[9];
  float* out = (float*)d_out;

  const int gE  = (N_EDGES + 255) / 256;
  const int gM  = (N_NODES + 63) / 64;
  const int gW  = (N_NODES + 3) / 4;
  const int gN256 = (N_NODES + 255) / 256;

  char* ws = (char*)d_ws;
  int* flag = (int*)ws;
  k_detect<<<1, 1024, 0, stream>>>(eidx, flag);

  const size_t need1 = 17410048;

  if (ws_size >= need1) {
    int*      bcnt  = (int*)(ws + 4096);
    int*      bbase = (int*)(ws + 57344);
    float*    Wcc   = (float*)(ws + 61440);     // 128x2 + c1[2] + bc[2]
    ushort*   bfWi  = (ushort*)(ws + 65536);    // 131072 B
    int*      off   = (int*)(ws + 262144);      // 400000 B
    float*    dinv  = (float*)(ws + 720896);    // 400000 B
    float*    g     = (float*)(ws + 1179648);   // 400000 B
    float4*   tbl   = (float4*)(ws + 1638400);  // 1600000 B
    float2*   tb2   = (float2*)(ws + 3407872);  // 800000 B
    int*      csr   = (int*)(ws + 4456448);     // 6400000 B
    unsigned* ebuf  = (unsigned*)(ws + 11010048); // 6400000 B

    // bucketed CSR build (LDS-aggregated, padded counters)
    k_zero<<<(NBKT * CPAD + 255) / 256, 256, 0, stream>>>(bcnt, NBKT * CPAD);
    k_binc<<<NBLK, 1024, 0, stream>>>(eidx, flag, bcnt);
    k_bscan<<<1, 1024, 0, stream>>>(bcnt, bbase);
    k_bin<<<NBLK, 1024, 0, stream>>>(eidx, flag, bcnt, ebuf);
    k_csr<<<NBKT, 256, 0, stream>>>(bbase, ebuf, off, dinv, csr);

    // weight prep: fragments for Wi; fully collapsed tail Wcc = W1@W2@Wh
    k_bsplit<<<16, 256, 0, stream>>>(Wi, 8, bfWi);
    k_wcc<<<1, 256, 0, stream>>>(W1, W2, Wh, b1, b2, bh, Wcc);

    // z = relu(x@Wi+bi) @ Wcc fused into GEMM epilogue -> tbl (N x float4)
    k_gemm_xz<DIM_IN><<<gM, 256, 0, stream>>>(x, bfWi, bi, Wcc, dinv, tbl);
    // two cheap 8-16 B/edge aggregation passes (L2-resident tables)
    k_aggr1<<<gN256, 256, 0, stream>>>(off, csr, tbl, tb2, g);
    k_aggr2<<<gN256, 256, 0, stream>>>(off, csr, tb2, dinv, g, Wcc + 256, out);
  } else {
    // fallback: fp32 atomic-scatter path (~103 MB)
    const int gN  = (N_NODES + 255) / 256;
    int*   off  = (int*)(ws + 4096);
    float* dinv = (float*)(ws + 404480);
    float* fbA  = (float*)(ws + 804864);
    float* fbB  = (float*)(ws + 804864 + (size_t)N_NODES * DIM_H * 4);
    const int gNH = (N_NODES * DIM_H + 255) / 256;
    const int gE2 = (N_EDGES + 1) / 2;
    k_zero<<<gN, 256, 0, stream>>>(off, N_NODES);
    k_count<<<gE, 256, 0, stream>>>(eidx, flag, off);
    k_dinv_old<<<gN, 256, 0, stream>>>(off, dinv);

    k_gemm<DIM_IN><<<gM, 256, 0, stream>>>(x, Wi, bi, nullptr, fbA, 1);
    k_gemm<DIM_H><<<gM, 256, 0, stream>>>(fbA, W1, nullptr, nullptr, fbB, 0);
    k_aggr_init<<<gNH, 256, 0, stream>>>(fbB, dinv, b1, fbA);
    k_aggr_edges<<<gE2, 256, 0, stream>>>(eidx, flag, fbB, dinv, fbA);
    k_gemm<DIM_H><<<gM, 256, 0, stream>>>(fbA, W2, nullptr, nullptr, fbB, 0);
    k_aggr_init<<<gNH, 256, 0, stream>>>(fbB, dinv, b2, fbA);
    k_aggr_edges<<<gE2, 256, 0, stream>>>(eidx, flag, fbB, dinv, fbA);
    k_head_f32<<<gW, 256, 0, stream>>>(fbA, Wh, bh, out);
  }
}